// Round 1
// baseline (737.071 us; speedup 1.0000x reference)
//
#include <hip/hip_runtime.h>
#include <stdint.h>

// Problem constants (from reference)
#define BB 2
#define SS 2048
#define DD 1024      // model dim
#define HH 4096      // hidden dim
#define EE 8         // experts
#define NTOK (BB*SS) // 4096 tokens
#define NPAIR (NTOK*2)

// GEMM tiling
#define BM 128
#define BN 128
#define BK 64
#define LDT 72       // padded LDS stride (bf16 elems): 144B rows, breaks pow2 conflicts

typedef float f32x4 __attribute__((ext_vector_type(4)));
typedef __bf16 bf16x8 __attribute__((ext_vector_type(8)));
typedef short s16x4 __attribute__((ext_vector_type(4)));
typedef short s16x8 __attribute__((ext_vector_type(8)));

__device__ __forceinline__ unsigned short f2bf(float f) {
    union { float f; uint32_t u; } v; v.f = f;
    return (unsigned short)((v.u + 0x7FFFu + ((v.u >> 16) & 1u)) >> 16);  // RNE
}

// ---------------------------------------------------------------------------
// Kernel 1: gating. One wave per token. f32 exact so top-k matches reference.
// Builds per-expert lists: tok (token idx), pid (pair slot = 2t+k), wgt (softmax prob).
// ---------------------------------------------------------------------------
__global__ __launch_bounds__(256) void gate_kernel(
    const float* __restrict__ x, const float* __restrict__ gw,
    const float* __restrict__ gb,
    int* __restrict__ cnt, int* __restrict__ tok, int* __restrict__ pid,
    float* __restrict__ wgt)
{
    int wave = threadIdx.x >> 6;
    int lane = threadIdx.x & 63;
    int t = blockIdx.x * 4 + wave;
    if (t >= NTOK) return;

    float acc[EE];
#pragma unroll
    for (int e = 0; e < EE; ++e) acc[e] = 0.f;

    const float* xr = x + (size_t)t * DD;
    for (int d = lane; d < DD; d += 64) {
        float xv = xr[d];
        const float* g = gw + (size_t)d * EE;
#pragma unroll
        for (int e = 0; e < EE; ++e) acc[e] += xv * g[e];
    }
#pragma unroll
    for (int e = 0; e < EE; ++e) {
#pragma unroll
        for (int off = 32; off >= 1; off >>= 1)
            acc[e] += __shfl_xor(acc[e], off);
    }
    if (lane == 0) {
        float lg[EE];
        float m = -1e30f;
#pragma unroll
        for (int e = 0; e < EE; ++e) { lg[e] = acc[e] + gb[e]; m = fmaxf(m, lg[e]); }
        float s = 0.f;
#pragma unroll
        for (int e = 0; e < EE; ++e) { lg[e] = expf(lg[e] - m); s += lg[e]; }
        float inv = 1.f / s;
        // top-2 (strict > keeps lowest index on ties, matching lax.top_k)
        int e0 = 0; float v0 = lg[0];
#pragma unroll
        for (int e = 1; e < EE; ++e) if (lg[e] > v0) { v0 = lg[e]; e0 = e; }
        int e1 = -1; float v1 = -1.f;
#pragma unroll
        for (int e = 0; e < EE; ++e) if (e != e0 && lg[e] > v1) { v1 = lg[e]; e1 = e; }

        int p0 = atomicAdd(&cnt[e0], 1);
        tok[e0 * NTOK + p0] = t; pid[e0 * NTOK + p0] = 2 * t;     wgt[e0 * NTOK + p0] = v0 * inv;
        int p1 = atomicAdd(&cnt[e1], 1);
        tok[e1 * NTOK + p1] = t; pid[e1 * NTOK + p1] = 2 * t + 1; wgt[e1 * NTOK + p1] = v1 * inv;
    }
}

// ---------------------------------------------------------------------------
// Kernel 2: pass A — hidden[pair] = relu(x[tok] @ w1[e] + b1[e]), bf16 out.
// Expert-grouped GEMM, tile 128x128, K=1024 in steps of 64. 256 thr / 4 waves.
// ---------------------------------------------------------------------------
__global__ __launch_bounds__(256) void ffn1_kernel(
    const float* __restrict__ x, const float* __restrict__ w1,
    const float* __restrict__ b1,
    const int* __restrict__ cnt, const int* __restrict__ tok,
    const int* __restrict__ pid,
    unsigned short* __restrict__ hid)
{
    const int e = blockIdx.z;
    const int mt = blockIdx.y;
    const int nt = blockIdx.x;
    const int Me = cnt[e];
    if (mt * BM >= Me) return;

    __shared__ short As[BM][LDT];
    __shared__ short Bs[BN][LDT];
    __shared__ int tl[BM];

    const int tid = threadIdx.x;
    if (tid < BM) {
        int p = mt * BM + tid;
        tl[tid] = (p < Me) ? tok[e * NTOK + p] : 0;
    }
    __syncthreads();

    const int lane = tid & 63;
    const int wv = tid >> 6;
    const int wr = wv >> 1, wc = wv & 1;

    f32x4 acc[4][4];
#pragma unroll
    for (int m = 0; m < 4; ++m)
#pragma unroll
        for (int n = 0; n < 4; ++n)
#pragma unroll
            for (int q = 0; q < 4; ++q) acc[m][n][q] = 0.f;

    const float* Bg = w1 + (size_t)e * DD * HH;   // [DD][HH] row-major
    const int nbase = nt * BN;

    for (int k0 = 0; k0 < DD; k0 += BK) {
        // Stage A: 128 rows x 64 k, f32 -> bf16. 16 lanes/row (float4 each).
#pragma unroll
        for (int r = 0; r < 8; ++r) {
            int row = r * 16 + (tid >> 4);
            int k4 = (tid & 15) * 4;
            const float4 v = *(const float4*)(x + (size_t)tl[row] * DD + k0 + k4);
            s16x4 b;
            b[0] = (short)f2bf(v.x); b[1] = (short)f2bf(v.y);
            b[2] = (short)f2bf(v.z); b[3] = (short)f2bf(v.w);
            *(s16x4*)&As[row][k4] = b;
        }
        // Stage B (transposed to [n][k]): task (n, kg): 8 strided f32 loads.
#pragma unroll
        for (int r = 0; r < 4; ++r) {
            int n = tid & 127;
            int kg = r * 2 + (tid >> 7);
            const float* src = Bg + (size_t)(k0 + kg * 8) * HH + nbase + n;
            s16x8 bb;
#pragma unroll
            for (int j = 0; j < 8; ++j) bb[j] = (short)f2bf(src[(size_t)j * HH]);
            *(s16x8*)&Bs[n][kg * 8] = bb;
        }
        __syncthreads();
#pragma unroll
        for (int ks = 0; ks < BK; ks += 32) {
            bf16x8 af[4], bfr[4];
            const int kb = ks + (lane >> 4) * 8;
#pragma unroll
            for (int m = 0; m < 4; ++m)
                af[m] = *(const bf16x8*)&As[wr * 64 + m * 16 + (lane & 15)][kb];
#pragma unroll
            for (int n = 0; n < 4; ++n)
                bfr[n] = *(const bf16x8*)&Bs[wc * 64 + n * 16 + (lane & 15)][kb];
#pragma unroll
            for (int m = 0; m < 4; ++m)
#pragma unroll
                for (int n = 0; n < 4; ++n)
                    acc[m][n] = __builtin_amdgcn_mfma_f32_16x16x32_bf16(af[m], bfr[n], acc[m][n], 0, 0, 0);
        }
        __syncthreads();
    }

    // Epilogue: +b1, relu, bf16 store to hidden[pair]
#pragma unroll
    for (int m = 0; m < 4; ++m) {
#pragma unroll
        for (int q = 0; q < 4; ++q) {
            int rloc = wr * 64 + m * 16 + (lane >> 4) * 4 + q;
            int p = mt * BM + rloc;
            if (p < Me) {
                int pp = pid[e * NTOK + p];
                unsigned short* dst = hid + (size_t)pp * HH;
#pragma unroll
                for (int n = 0; n < 4; ++n) {
                    int ng = nbase + wc * 64 + n * 16 + (lane & 15);
                    float h = acc[m][n][q] + b1[(size_t)e * HH + ng];
                    dst[ng] = f2bf(fmaxf(h, 0.f));
                }
            }
        }
    }
}

// ---------------------------------------------------------------------------
// Kernel 3: pass B — out[tok] += wgt * (hidden[pair] @ w2[e] + b2[e]).
// Expert-grouped GEMM, K=4096 in steps of 64, atomicAdd f32 into zeroed out.
// ---------------------------------------------------------------------------
__global__ __launch_bounds__(256) void ffn2_kernel(
    const unsigned short* __restrict__ hid, const float* __restrict__ w2,
    const float* __restrict__ b2,
    const int* __restrict__ cnt, const int* __restrict__ tok,
    const int* __restrict__ pid, const float* __restrict__ wgt,
    float* __restrict__ out)
{
    const int e = blockIdx.z;
    const int mt = blockIdx.y;
    const int nt = blockIdx.x;
    const int Me = cnt[e];
    if (mt * BM >= Me) return;

    __shared__ short As[BM][LDT];
    __shared__ short Bs[BN][LDT];
    __shared__ int pl[BM];

    const int tid = threadIdx.x;
    if (tid < BM) {
        int p = mt * BM + tid;
        pl[tid] = (p < Me) ? pid[e * NTOK + p] : 0;
    }
    __syncthreads();

    const int lane = tid & 63;
    const int wv = tid >> 6;
    const int wr = wv >> 1, wc = wv & 1;

    f32x4 acc[4][4];
#pragma unroll
    for (int m = 0; m < 4; ++m)
#pragma unroll
        for (int n = 0; n < 4; ++n)
#pragma unroll
            for (int q = 0; q < 4; ++q) acc[m][n][q] = 0.f;

    const float* Bg = w2 + (size_t)e * HH * DD;   // [HH][DD] row-major
    const int nbase = nt * BN;

    for (int k0 = 0; k0 < HH; k0 += BK) {
        // Stage A from bf16 hidden: 8 lanes/row, 16B each, 32 rows/round.
#pragma unroll
        for (int r = 0; r < 4; ++r) {
            int row = r * 32 + (tid >> 3);
            int k8 = (tid & 7) * 8;
            s16x8 v = *(const s16x8*)(hid + (size_t)pl[row] * HH + k0 + k8);
            *(s16x8*)&As[row][k8] = v;
        }
        // Stage B transposed, ldB = DD
#pragma unroll
        for (int r = 0; r < 4; ++r) {
            int n = tid & 127;
            int kg = r * 2 + (tid >> 7);
            const float* src = Bg + (size_t)(k0 + kg * 8) * DD + nbase + n;
            s16x8 bb;
#pragma unroll
            for (int j = 0; j < 8; ++j) bb[j] = (short)f2bf(src[(size_t)j * DD]);
            *(s16x8*)&Bs[n][kg * 8] = bb;
        }
        __syncthreads();
#pragma unroll
        for (int ks = 0; ks < BK; ks += 32) {
            bf16x8 af[4], bfr[4];
            const int kb = ks + (lane >> 4) * 8;
#pragma unroll
            for (int m = 0; m < 4; ++m)
                af[m] = *(const bf16x8*)&As[wr * 64 + m * 16 + (lane & 15)][kb];
#pragma unroll
            for (int n = 0; n < 4; ++n)
                bfr[n] = *(const bf16x8*)&Bs[wc * 64 + n * 16 + (lane & 15)][kb];
#pragma unroll
            for (int m = 0; m < 4; ++m)
#pragma unroll
                for (int n = 0; n < 4; ++n)
                    acc[m][n] = __builtin_amdgcn_mfma_f32_16x16x32_bf16(af[m], bfr[n], acc[m][n], 0, 0, 0);
        }
        __syncthreads();
    }

    // Epilogue: scale by gate weight, add b2, atomicAdd into out[token]
#pragma unroll
    for (int m = 0; m < 4; ++m) {
#pragma unroll
        for (int q = 0; q < 4; ++q) {
            int rloc = wr * 64 + m * 16 + (lane >> 4) * 4 + q;
            int p = mt * BM + rloc;
            if (p < Me) {
                int t = tok[e * NTOK + p];
                float wvv = wgt[e * NTOK + p];
                float* dst = out + (size_t)t * DD;
#pragma unroll
                for (int n = 0; n < 4; ++n) {
                    int ng = nbase + wc * 64 + n * 16 + (lane & 15);
                    float val = wvv * (acc[m][n][q] + b2[(size_t)e * DD + ng]);
                    atomicAdd(&dst[ng], val);
                }
            }
        }
    }
}

// ---------------------------------------------------------------------------
// Workspace layout (bytes):
//   [0, 256)                      cnt[8]  (int, memset to 0 each call)
//   [256, +128K)                  tok[E][NTOK] int
//   [+128K, +256K)                pid[E][NTOK] int
//   [+256K, +384K)                wgt[E][NTOK] float
//   [393472, +64M)                hid[NPAIR][HH] bf16  (67,108,864 B)
// Total ~67.5 MB.
// ---------------------------------------------------------------------------
extern "C" void kernel_launch(void* const* d_in, const int* in_sizes, int n_in,
                              void* d_out, int out_size, void* d_ws, size_t ws_size,
                              hipStream_t stream) {
    const float* x   = (const float*)d_in[0];
    const float* gw  = (const float*)d_in[1];
    const float* gb  = (const float*)d_in[2];
    const float* w1  = (const float*)d_in[3];
    const float* b1  = (const float*)d_in[4];
    const float* w2  = (const float*)d_in[5];
    const float* b2  = (const float*)d_in[6];
    float* out = (float*)d_out;

    char* ws = (char*)d_ws;
    int*   cnt = (int*)ws;
    int*   tok = (int*)(ws + 256);
    int*   pid = (int*)(ws + 256 + 4 * EE * NTOK);
    float* wgt = (float*)(ws + 256 + 8 * EE * NTOK);
    unsigned short* hid = (unsigned short*)(ws + 256 + 12 * EE * NTOK);

    hipMemsetAsync(cnt, 0, 256, stream);
    hipMemsetAsync(out, 0, (size_t)out_size * sizeof(float), stream);

    gate_kernel<<<NTOK / 4, 256, 0, stream>>>(x, gw, gb, cnt, tok, pid, wgt);

    // Worst-case grids (data-dependent early exit on cnt[e])
    ffn1_kernel<<<dim3(HH / BN, NTOK / BM, EE), 256, 0, stream>>>(
        x, w1, b1, cnt, tok, pid, hid);
    ffn2_kernel<<<dim3(DD / BN, NTOK / BM, EE), 256, 0, stream>>>(
        hid, w2, b2, cnt, tok, pid, wgt, out);
}